// Round 19
// baseline (6289.387 us; speedup 1.0000x reference)
//
#include <hip/hip_runtime.h>
#include <math.h>

#define NB 8
#define NT 1024
#define ND 128
#define NS 8
#define NH 4
#define NOUT 32000

typedef _Float16 f16x8 __attribute__((ext_vector_type(8)));
typedef float f32x4 __attribute__((ext_vector_type(4)));

// rcp-based activations (v_rcp_f32: 1-ulp, ~1e-7 rel err -- harmless here).
__device__ __forceinline__ float rsigm(float x) {
    return __builtin_amdgcn_rcpf(1.0f + __expf(-x));
}
__device__ __forceinline__ float ftanh(float x) {
    float ax = fabsf(x);
    float e = __expf(-2.0f * ax);
    float t = (1.0f - e) * __builtin_amdgcn_rcpf(1.0f + e);
    return copysignf(t, x);
}
__device__ __forceinline__ float dot4(float4 a, float4 b) {
    return a.x * b.x + a.y * b.y + a.z * b.z + a.w * b.w;
}

// Cross-lane add via DPP (1-cycle VALU).  0xB1 = quad_perm lane^1,
// 0x4E = quad_perm lane^2, 0x141 = ROW_HALF_MIRROR (completes the 8-sum).
#define QPADD(v, ctrl)                                                             \
    (v) += __int_as_float(__builtin_amdgcn_update_dpp(                             \
        0, __float_as_int(v), (ctrl), 0xF, 0xF, true))

// Raw barrier: LDS-visibility only (no vmcnt drain).
#define BAR()                                              \
    {                                                      \
        asm volatile("s_waitcnt lgkmcnt(0)" ::: "memory"); \
        __builtin_amdgcn_s_barrier();                      \
        asm volatile("" ::: "memory");                     \
    }

// ---------------------------------------------------------------------------
// Kernel W1: Wow = Wo @ Wv, bvo = Wo @ bv   (v@Wo^T == nw@Wow^T + bvo)
// ---------------------------------------------------------------------------
__global__ __launch_bounds__(128) void k_wow(
    const float* __restrict__ Wo, const float* __restrict__ Wv,
    const float* __restrict__ bv, float* __restrict__ Wow, float* __restrict__ bvo) {
    int j = blockIdx.x;
    int k = threadIdx.x;
    __shared__ float woj[ND];
    woj[k] = Wo[j * ND + k];
    __syncthreads();
    float acc = 0.f;
#pragma unroll 8
    for (int d = 0; d < ND; ++d) acc += woj[d] * Wv[d * ND + k];
    Wow[j * ND + k] = acc;
    if (k == 0) {
        float s = 0.f;
        for (int d = 0; d < ND; ++d) s += bv[d] * woj[d];
        bvo[j] = s;
    }
}

// ---------------------------------------------------------------------------
// Kernel 0: pack 8 weight matrices into MFMA B-frag order, dual-fp16
// (hi + lo*2^11).  Layout: f16x8 unit = m*4096 + f*512 + t, f=kt*2+pl,
// t=w*64+lane: value W[col][k], col=16w+(lane&15), k=kt*32+8*(lane>>4)+i.
// mats: 0 z,1 r,2 h,3 q(pre-scaled by 1/sqrt(32)),4 k,5 vo(=Wow),6 c1,7 c2
// ---------------------------------------------------------------------------
__global__ __launch_bounds__(256) void k_pack(
    const float* __restrict__ Wz, const float* __restrict__ Wr, const float* __restrict__ Wh,
    const float* __restrict__ Wq, const float* __restrict__ Wk, const float* __restrict__ Wow,
    const float* __restrict__ Wc, _Float16* __restrict__ wpack) {
    int linear = blockIdx.x * 256 + threadIdx.x;   // m*4096 + f*512 + t
    int m = linear >> 12;
    int rem = linear & 4095;
    int f = rem >> 9;
    int t = rem & 511;
    int kt = f >> 1, pl = f & 1;
    int w = t >> 6, lane = t & 63;
    int col = 16 * w + (lane & 15);
    int kk = kt * 32 + 8 * (lane >> 4);
    const float* src;
    int stride, koff = 0;
    float mult = 1.0f;
    switch (m) {
        case 0: src = Wz; stride = 256; break;
        case 1: src = Wr; stride = 256; break;
        case 2: src = Wh; stride = 256; break;
        case 3: src = Wq; stride = 128; mult = 0.17677669529663687f; break;
        case 4: src = Wk; stride = 128; break;
        case 5: src = Wow; stride = 128; break;             // fused v->o
        case 6: src = Wc; stride = 256; break;              // c1 (new half)
        default: src = Wc; stride = 256; koff = 128; break; // c2 (attn half)
    }
    const float* p = src + (size_t)col * stride + koff + kk;
    f16x8 out;
#pragma unroll
    for (int i = 0; i < 8; ++i) {
        float v = p[i] * mult;
        _Float16 h = (_Float16)v;
        out[i] = pl ? (_Float16)((v - (float)h) * 2048.0f) : h;
    }
    *(f16x8*)(wpack + (size_t)linear * 8) = out;
}

// ---------------------------------------------------------------------------
// Kernel 1: embedding gather + x-half of z/r/h gate preactivations (+bias)
// ---------------------------------------------------------------------------
__global__ __launch_bounds__(128) void k_embed_xproj(
    const int* __restrict__ x, const float* __restrict__ emb,
    const float* __restrict__ Wz, const float* __restrict__ bz,
    const float* __restrict__ Wr, const float* __restrict__ br,
    const float* __restrict__ Wh, const float* __restrict__ bh,
    float* __restrict__ xproj) {
    int bt = blockIdx.x;
    int j = threadIdx.x;
    __shared__ float xe[ND];
    long tok = (long)x[bt];
    xe[j] = emb[tok * ND + j];
    __syncthreads();
    const float4* xe4 = (const float4*)xe;
    const float4* wz = (const float4*)(Wz + j * 2 * ND + ND);
    const float4* wr = (const float4*)(Wr + j * 2 * ND + ND);
    const float4* wh = (const float4*)(Wh + j * 2 * ND + ND);
    float az = bz[j], ar = br[j], ah = bh[j];
#pragma unroll 8
    for (int k = 0; k < ND / 4; ++k) {
        float4 xv = xe4[k];
        az += dot4(wz[k], xv);
        ar += dot4(wr[k], xv);
        ah += dot4(wh[k], xv);
    }
    float* o = xproj + (long)bt * 3 * ND;
    o[j] = az;
    o[ND + j] = ar;
    o[2 * ND + j] = ah;
}

// ---------------------------------------------------------------------------
// Kernel 2: the scan.  8 blocks (1 batch each) x 512 threads (8 waves,
// 2 waves/SIMD).  R18 structure (best: 5.83 ms scan) + 3 zero-register
// shavings: (1) atv kept in regs across D->F (no plane readback),
// (2) MM/MM_HL lo-chains split into two 4-deep accumulators,
// (3) softmax scale folded into q pack.
// ---------------------------------------------------------------------------
__global__ __launch_bounds__(512, 2) void k_scan(
    const float* __restrict__ xproj, const float* __restrict__ init_states,
    const _Float16* __restrict__ wpack, const float* __restrict__ bvo,
    const float* __restrict__ bq, const float* __restrict__ bk,
    const float* __restrict__ bo, const float* __restrict__ bc,
    float* __restrict__ stout) {
    const int b = blockIdx.x, tid = threadIdx.x;
    const int lane = tid & 63, w = tid >> 6;
    const int lrow = lane & 15, lkb = lane >> 4;
    const int c = 16 * w + lrow;            // owned output column
    const bool vrow = (lkb < 2);            // C rows 4*lkb+i < 8 are real

    __shared__ float qf[NS][132], kf[NS][132];
    __shared__ float vofT[ND][8];           // transposed vo: [col][state-row]
    __shared__ float pf[8][NS][NS];
    // fp16 planes [8][128], XOR-swizzled.  0/1 st, 2/3 rs, 4/5 nw, 6/7 at.
    __shared__ _Float16 hp[8][8 * 128];
    // LDS-resident weight HI-planes, conflict-free [kt*512+t] (32 KB each)
    __shared__ f16x8 wzh[2048], wrh[2048], whh[2048], wqh[2048];

#define LOADW(BH, BL, m)                                                          \
    {                                                                             \
        const f16x8* base_ = (const f16x8*)wpack + ((m) << 12);                   \
        _Pragma("unroll") for (int kt_ = 0; kt_ < 4; ++kt_) {                     \
            BH[kt_] = base_[((kt_ * 2 + 0) << 9) + tid];                          \
            BL[kt_] = base_[((kt_ * 2 + 1) << 9) + tid];                          \
        }                                                                         \
    }

    // A-frag read: pad rows (lrow>=8) read row lrow&7 -> C pad rows duplicate
#define LDA(ph, pl_)                                                              \
    {                                                                             \
        _Pragma("unroll") for (int kt_ = 0; kt_ < 4; ++kt_) {                     \
            int off_ = ((lrow & 7) * 256 + kt_ * 64 + lkb * 16) ^ ((lrow & 7) << 4); \
            ah[kt_] = *(const f16x8*)((const char*)(ph) + off_);                  \
            al[kt_] = *(const f16x8*)((const char*)(pl_) + off_);                 \
        }                                                                         \
    }

    // B-frags fully from registers/L2 stream; lo split into two 4-deep chains
#define MM(res, BH, BL, init0)                                                    \
    {                                                                             \
        f32x4 xh_ = {(init0), (init0), (init0), (init0)};                         \
        f32x4 xl1_ = {0.f, 0.f, 0.f, 0.f}, xl2_ = {0.f, 0.f, 0.f, 0.f};           \
        _Pragma("unroll") for (int kt_ = 0; kt_ < 4; ++kt_) {                     \
            xh_ = __builtin_amdgcn_mfma_f32_16x16x32_f16(ah[kt_], BH[kt_], xh_, 0, 0, 0);   \
            xl1_ = __builtin_amdgcn_mfma_f32_16x16x32_f16(al[kt_], BH[kt_], xl1_, 0, 0, 0); \
            xl2_ = __builtin_amdgcn_mfma_f32_16x16x32_f16(ah[kt_], BL[kt_], xl2_, 0, 0, 0); \
        }                                                                         \
        _Pragma("unroll") for (int i_ = 0; i_ < 4; ++i_)                          \
            res[i_] = xh_[i_] + (xl1_[i_] + xl2_[i_]) * 4.8828125e-4f;            \
    }

    // B hi from LDS plane, B lo streamed from L2 at the site; lo chains split
#define MM_HL(res, WH, m, init0)                                                  \
    {                                                                             \
        const f16x8* base_ = (const f16x8*)wpack + ((m) << 12);                   \
        f32x4 xh_ = {(init0), (init0), (init0), (init0)};                         \
        f32x4 xl1_ = {0.f, 0.f, 0.f, 0.f}, xl2_ = {0.f, 0.f, 0.f, 0.f};           \
        _Pragma("unroll") for (int kt_ = 0; kt_ < 4; ++kt_) {                     \
            f16x8 bh_ = WH[(kt_ << 9) + tid];                                     \
            f16x8 bl_ = base_[((kt_ * 2 + 1) << 9) + tid];                        \
            xh_ = __builtin_amdgcn_mfma_f32_16x16x32_f16(ah[kt_], bh_, xh_, 0, 0, 0);   \
            xl1_ = __builtin_amdgcn_mfma_f32_16x16x32_f16(al[kt_], bh_, xl1_, 0, 0, 0); \
            xl2_ = __builtin_amdgcn_mfma_f32_16x16x32_f16(ah[kt_], bl_, xl2_, 0, 0, 0); \
        }                                                                         \
        _Pragma("unroll") for (int i_ = 0; i_ < 4; ++i_)                          \
            res[i_] = xh_[i_] + (xl1_[i_] + xl2_[i_]) * 4.8828125e-4f;            \
    }

#define WRHL(pih, pil, row_, col_, val_)                                          \
    {                                                                             \
        float v_ = (val_);                                                        \
        _Float16 h_ = (_Float16)v_;                                               \
        _Float16 l_ = (_Float16)((v_ - (float)h_) * 2048.0f);                     \
        int off_ = ((row_)*256 + (col_)*2) ^ (((row_)&7) << 4);                   \
        *(_Float16*)((char*)hp[pih] + off_) = h_;                                 \
        *(_Float16*)((char*)hp[pil] + off_) = l_;                                 \
    }

    // ---- prologue: z,r,h,q HI planes into LDS ----
    {
        const f16x8* wp8 = (const f16x8*)wpack;
        for (int i = tid; i < 2048; i += 512) {
            int kt = i >> 9, tt = i & 511;
            wzh[i] = wp8[(0 << 12) + ((kt * 2 + 0) << 9) + tt];
            wrh[i] = wp8[(1 << 12) + ((kt * 2 + 0) << 9) + tt];
            whh[i] = wp8[(2 << 12) + ((kt * 2 + 0) << 9) + tt];
            wqh[i] = wp8[(3 << 12) + ((kt * 2 + 0) << 9) + tt];
        }
    }

    // ---- init: state fp32 into registers, hi/lo into st planes (rows 0-7) ----
    float stv[4];
#pragma unroll
    for (int i = 0; i < 4; ++i) {
        int r = 4 * lkb + i;
        float v = init_states[(r & 7) * ND + c];
        stv[i] = v;
        if (vrow) WRHL(0, 1, r, c, v);
    }

    // L2-streamed weights: k (resident if regalloc allows; remat accepted)
    f16x8 Bkh[4], Bkl[4];
    LOADW(Bkh, Bkl, 4);
    // rotating stream buffer: vo -> c1 -> c2 -> vo(t+1) ...
    f16x8 Sh[4], Sl[4];
    LOADW(Sh, Sl, 5);  // vo for t=0

    // bq pre-scaled to match the pre-scaled q weights
    const float bqv = bq[c] * 0.17677669529663687f;
    const float bkv = bk[c], bvoc = bvo[c], bov = bo[c], bcv = bc[c];

    f16x8 ah[4], al[4];
    float zv[4], nwv[4], atv[4];
    f32x4 ach, acl1, acl2;

    // xproj prefetch for t=0
    const float* xpb = xproj + ((size_t)b * NT) * 3 * ND;
    float xz = xpb[c], xr = xpb[ND + c], xh = xpb[2 * ND + c];

    BAR();

    for (int t = 0; t < NT; ++t) {
        // ---- A: z, r gates (hi-LDS / lo-L2), write r*state ----
        LDA(hp[0], hp[1]);
        float zp[4], rp[4];
        MM_HL(zp, wzh, 0, xz);
        MM_HL(rp, wrh, 1, xr);
#pragma unroll
        for (int i = 0; i < 4; ++i) zv[i] = rsigm(zp[i]);
        if (vrow) {
#pragma unroll
            for (int i = 0; i < 4; ++i) {
                float rs_ = rsigm(rp[i]) * stv[i];
                WRHL(2, 3, 4 * lkb + i, c, rs_);
            }
        }
        BAR();
        // ---- B: cand/new (hi-LDS / lo-L2) ----
        LDA(hp[2], hp[3]);
        float hpre[4];
        MM_HL(hpre, whh, 2, xh);
#pragma unroll
        for (int i = 0; i < 4; ++i) {
            float cand = ftanh(hpre[i]);
            float nv = (1.0f - zv[i]) * stv[i] + zv[i] * cand;
            nwv[i] = nv;
        }
        if (vrow) {
#pragma unroll
            for (int i = 0; i < 4; ++i) WRHL(4, 5, 4 * lkb + i, c, nwv[i]);
        }
        BAR();
        // ---- C: q (hi-LDS / lo-L2), k (L2), vo (stream) ----
        LDA(hp[4], hp[5]);  // nw fragments; stay live through D (c1)
        {
            float qp[4];
            MM_HL(qp, wqh, 3, bqv);
            if (vrow) {
#pragma unroll
                for (int i = 0; i < 4; ++i) qf[4 * lkb + i][c] = qp[i];
            }
            float kp[4];
            MM(kp, Bkh, Bkl, bkv);
            if (vrow) {
#pragma unroll
                for (int i = 0; i < 4; ++i) kf[4 * lkb + i][c] = kp[i];
            }
            float vp[4];
            MM(vp, Sh, Sl, bvoc);  // vo = nw@Wow^T + bvo
            LOADW(Sh, Sl, 6);      // stream c1
            if (vrow) {
                float4 vv;
                vv.x = vp[0]; vv.y = vp[1]; vv.z = vp[2]; vv.w = vp[3];
                *(float4*)&vofT[c][4 * lkb] = vv;  // one b128, transposed
            }
        }
        BAR();
        // ---- D: softmax (no-max, DPP-only reduce) + c1 + PV(-> at planes) ----
        {
            int hh = w >> 1;
            int sq = lane >> 3, skv = lane & 7;
            float s_ = 0.f;
#pragma unroll
            for (int j = 0; j < 8; ++j) {
                float4 qv = *(const float4*)&qf[sq][32 * hh + 4 * j];
                float4 kv4 = *(const float4*)&kf[skv][32 * hh + 4 * j];
                s_ += dot4(qv, kv4);
            }
            // scale folded into q pack; scores O(1..10): no-max is identical.
            float e_ = __expf(s_);
            float sm = e_;
            QPADD(sm, 0xB1);    // lane^1 (quad_perm)
            QPADD(sm, 0x4E);    // lane^2 (quad_perm)
            QPADD(sm, 0x141);   // other quad (ROW_HALF_MIRROR)
            pf[w][sq][skv] = e_ * __builtin_amdgcn_rcpf(sm);
        }
        // c1 accumulate (ah/al still = nw fragments); S = c1
        ach = (f32x4){bcv, bcv, bcv, bcv};
        acl1 = (f32x4){0.f, 0.f, 0.f, 0.f};
        acl2 = (f32x4){0.f, 0.f, 0.f, 0.f};
#pragma unroll
        for (int kt_ = 0; kt_ < 4; ++kt_) {
            ach = __builtin_amdgcn_mfma_f32_16x16x32_f16(ah[kt_], Sh[kt_], ach, 0, 0, 0);
            acl1 = __builtin_amdgcn_mfma_f32_16x16x32_f16(al[kt_], Sh[kt_], acl1, 0, 0, 0);
            acl2 = __builtin_amdgcn_mfma_f32_16x16x32_f16(ah[kt_], Sl[kt_], acl2, 0, 0, 0);
        }
        LOADW(Sh, Sl, 7);  // stream c2
        // PV: at = bo + P @ vo; keep atv in regs for F (planes still written
        // for F's LDA -- the c2 MFMA A-operand needs all-column fragments)
        if (vrow) {
            float4 voa = *(const float4*)&vofT[c][0];
            float4 vob = *(const float4*)&vofT[c][4];
#pragma unroll
            for (int i = 0; i < 4; ++i) {
                int r = 4 * lkb + i, pq = r & 7;
                float4 pa = *(const float4*)&pf[w][pq][0];
                float4 pb = *(const float4*)&pf[w][pq][4];
                float acc = bov + dot4(pa, voa) + dot4(pb, vob);
                atv[i] = acc;
                WRHL(6, 7, r, c, acc);
            }
        }
        BAR();
        // ---- F: c2 + gate blend -> state regs + st planes ----
        LDA(hp[6], hp[7]);  // at fragments (A-operand of c2)
#pragma unroll
        for (int kt_ = 0; kt_ < 4; ++kt_) {
            ach = __builtin_amdgcn_mfma_f32_16x16x32_f16(ah[kt_], Sh[kt_], ach, 0, 0, 0);
            acl1 = __builtin_amdgcn_mfma_f32_16x16x32_f16(al[kt_], Sh[kt_], acl1, 0, 0, 0);
            acl2 = __builtin_amdgcn_mfma_f32_16x16x32_f16(ah[kt_], Sl[kt_], acl2, 0, 0, 0);
        }
        LOADW(Sh, Sl, 5);  // stream vo for t+1 (dead on last iter, harmless)
        if (vrow) {
#pragma unroll
            for (int i = 0; i < 4; ++i) {
                float g = rsigm(ach[i] + (acl1[i] + acl2[i]) * 4.8828125e-4f);
                float sv = g * nwv[i] + (1.0f - g) * atv[i];
                stv[i] = sv;
                WRHL(0, 1, 4 * lkb + i, c, sv);
            }
        }
        // xproj prefetch for t+1
        {
            int tn = (t + 1 < NT) ? t + 1 : t;
            const float* xpn = xproj + ((size_t)(b * NT + tn)) * 3 * ND;
            xz = xpn[c];
            xr = xpn[ND + c];
            xh = xpn[2 * ND + c];
        }
        BAR();
    }
    if (vrow) {
#pragma unroll
        for (int i = 0; i < 4; ++i) {
            int r = 4 * lkb + i;
            stout[(size_t)b * NS * ND + r * ND + c] = stv[i];
        }
    }
#undef LOADW
#undef LDA
#undef MM
#undef MM_HL
#undef WRHL
}

// ---------------------------------------------------------------------------
// Kernel 3: out[b][o] = stflat[b] . Wout[o] + bout[o].  One wave per row.
// ---------------------------------------------------------------------------
__global__ __launch_bounds__(512) void k_out(
    const float* __restrict__ stflat, const float* __restrict__ Wout,
    const float* __restrict__ bout, float* __restrict__ out) {
    __shared__ float stl[NB][NS * ND];
    int tid = threadIdx.x;
    for (int idx = tid; idx < NB * NS * ND; idx += 512)
        stl[idx >> 10][idx & 1023] = stflat[idx];
    __syncthreads();
    int wave = tid >> 6, lane = tid & 63;
    int o = blockIdx.x * 8 + wave;
    float acc[NB];
#pragma unroll
    for (int b = 0; b < NB; ++b) acc[b] = 0.0f;
    const float4* wrow = (const float4*)(Wout + (size_t)o * (NS * ND));
#pragma unroll
    for (int i = 0; i < 4; ++i) {
        float4 wv = wrow[i * 64 + lane];
        int kb = (i * 64 + lane) * 4;
#pragma unroll
        for (int b = 0; b < NB; ++b) {
            float4 sv = *(const float4*)&stl[b][kb];
            acc[b] += dot4(wv, sv);
        }
    }
#pragma unroll
    for (int off = 32; off; off >>= 1) {
#pragma unroll
        for (int b = 0; b < NB; ++b) acc[b] += __shfl_down(acc[b], off);
    }
    if (lane == 0) {
        float bb = bout[o];
#pragma unroll
        for (int b = 0; b < NB; ++b) out[(size_t)b * NOUT + o] = acc[b] + bb;
    }
}

extern "C" void kernel_launch(void* const* d_in, const int* in_sizes, int n_in,
                              void* d_out, int out_size, void* d_ws, size_t ws_size,
                              hipStream_t stream) {
    const int* x = (const int*)d_in[0];
    const float* emb = (const float*)d_in[1];
    const float* init_states = (const float*)d_in[2];
    const float* Wz = (const float*)d_in[3];
    const float* bz = (const float*)d_in[4];
    const float* Wr = (const float*)d_in[5];
    const float* br = (const float*)d_in[6];
    const float* Wh = (const float*)d_in[7];
    const float* bh = (const float*)d_in[8];
    const float* Wq = (const float*)d_in[9];
    const float* bq = (const float*)d_in[10];
    const float* Wk = (const float*)d_in[11];
    const float* bk = (const float*)d_in[12];
    const float* Wv = (const float*)d_in[13];
    const float* bv = (const float*)d_in[14];
    const float* Wo = (const float*)d_in[15];
    const float* bo = (const float*)d_in[16];
    const float* Wc = (const float*)d_in[17];
    const float* bc = (const float*)d_in[18];
    const float* Wout = (const float*)d_in[19];
    const float* bout = (const float*)d_in[20];
    float* out = (float*)d_out;

    float* xproj = (float*)d_ws;                           // 12.58 MB
    float* stflat = xproj + (size_t)NB * NT * 3 * ND;      // 32 KB
    _Float16* wpack = (_Float16*)(stflat + NB * NS * ND);  // 8*4096*8 f16 = 512 KB
    float* Wow = (float*)(wpack + (size_t)8 * 4096 * 8);   // 64 KB
    float* bvo = Wow + ND * ND;                            // 512 B

    k_wow<<<ND, ND, 0, stream>>>(Wo, Wv, bv, Wow, bvo);
    k_pack<<<128, 256, 0, stream>>>(Wz, Wr, Wh, Wq, Wk, Wow, Wc, wpack);
    k_embed_xproj<<<NB * NT, 128, 0, stream>>>(x, emb, Wz, bz, Wr, br, Wh, bh, xproj);
    k_scan<<<NB, 512, 0, stream>>>(xproj, init_states, wpack, bvo, bq, bk, bo, bc, stflat);
    k_out<<<NOUT / 8, 512, 0, stream>>>(stflat, Wout, bout, out);
}

// Round 20
// 6053.687 us; speedup vs baseline: 1.0389x; 1.0389x over previous
//
#include <hip/hip_runtime.h>
#include <math.h>

#define NB 8
#define NT 1024
#define ND 128
#define NS 8
#define NH 4
#define NOUT 32000

typedef _Float16 f16x8 __attribute__((ext_vector_type(8)));
typedef float f32x4 __attribute__((ext_vector_type(4)));

// rcp-based activations (v_rcp_f32: 1-ulp, ~1e-7 rel err -- harmless here;
// avoids the ~8-instr v_div_scale/fmas/fixup expansion of fp32 division).
__device__ __forceinline__ float rsigm(float x) {
    return __builtin_amdgcn_rcpf(1.0f + __expf(-x));
}
__device__ __forceinline__ float ftanh(float x) {
    float ax = fabsf(x);
    float e = __expf(-2.0f * ax);
    float t = (1.0f - e) * __builtin_amdgcn_rcpf(1.0f + e);
    return copysignf(t, x);
}
__device__ __forceinline__ float dot4(float4 a, float4 b) {
    return a.x * b.x + a.y * b.y + a.z * b.z + a.w * b.w;
}

// Cross-lane add via DPP (1-cycle VALU; no LDS-pipe shuffle latency).
// 0xB1 = quad_perm lane^1, 0x4E = quad_perm lane^2, 0x141 = ROW_HALF_MIRROR
// (after xor1+xor2 every lane holds its quad sum; half-mirror pairs each
// lane with the OTHER quad: 0<->7,1<->6,2<->5,3<->4 -- completes the 8-sum).
#define QPADD(v, ctrl)                                                             \
    (v) += __int_as_float(__builtin_amdgcn_update_dpp(                             \
        0, __float_as_int(v), (ctrl), 0xF, 0xF, true))

// Raw barrier: LDS-visibility only (no vmcnt drain).
#define BAR()                                              \
    {                                                      \
        asm volatile("s_waitcnt lgkmcnt(0)" ::: "memory"); \
        __builtin_amdgcn_s_barrier();                      \
        asm volatile("" ::: "memory");                     \
    }

// ---------------------------------------------------------------------------
// Kernel W1: Wow = Wo @ Wv, bvo = Wo @ bv   (v@Wo^T == nw@Wow^T + bvo)
// ---------------------------------------------------------------------------
__global__ __launch_bounds__(128) void k_wow(
    const float* __restrict__ Wo, const float* __restrict__ Wv,
    const float* __restrict__ bv, float* __restrict__ Wow, float* __restrict__ bvo) {
    int j = blockIdx.x;
    int k = threadIdx.x;
    __shared__ float woj[ND];
    woj[k] = Wo[j * ND + k];
    __syncthreads();
    float acc = 0.f;
#pragma unroll 8
    for (int d = 0; d < ND; ++d) acc += woj[d] * Wv[d * ND + k];
    Wow[j * ND + k] = acc;
    if (k == 0) {
        float s = 0.f;
        for (int d = 0; d < ND; ++d) s += bv[d] * woj[d];
        bvo[j] = s;
    }
}

// ---------------------------------------------------------------------------
// Kernel 0: pack 8 weight matrices into MFMA B-frag order, dual-fp16
// (hi + lo*2^11).  Layout: f16x8 unit = m*4096 + f*512 + t, f=kt*2+pl,
// t=w*64+lane: value W[col][k], col=16w+(lane&15), k=kt*32+8*(lane>>4)+i.
// mats: 0 z,1 r,2 h,3 q(pre-scaled by 1/sqrt(32)),4 k,5 vo(=Wow),6 c1,7 c2
// ---------------------------------------------------------------------------
__global__ __launch_bounds__(256) void k_pack(
    const float* __restrict__ Wz, const float* __restrict__ Wr, const float* __restrict__ Wh,
    const float* __restrict__ Wq, const float* __restrict__ Wk, const float* __restrict__ Wow,
    const float* __restrict__ Wc, _Float16* __restrict__ wpack) {
    int linear = blockIdx.x * 256 + threadIdx.x;   // m*4096 + f*512 + t
    int m = linear >> 12;
    int rem = linear & 4095;
    int f = rem >> 9;
    int t = rem & 511;
    int kt = f >> 1, pl = f & 1;
    int w = t >> 6, lane = t & 63;
    int col = 16 * w + (lane & 15);
    int kk = kt * 32 + 8 * (lane >> 4);
    const float* src;
    int stride, koff = 0;
    float mult = 1.0f;
    switch (m) {
        case 0: src = Wz; stride = 256; break;
        case 1: src = Wr; stride = 256; break;
        case 2: src = Wh; stride = 256; break;
        case 3: src = Wq; stride = 128; mult = 0.17677669529663687f; break;
        case 4: src = Wk; stride = 128; break;
        case 5: src = Wow; stride = 128; break;             // fused v->o
        case 6: src = Wc; stride = 256; break;              // c1 (new half)
        default: src = Wc; stride = 256; koff = 128; break; // c2 (attn half)
    }
    const float* p = src + (size_t)col * stride + koff + kk;
    f16x8 out;
#pragma unroll
    for (int i = 0; i < 8; ++i) {
        float v = p[i] * mult;
        _Float16 h = (_Float16)v;
        out[i] = pl ? (_Float16)((v - (float)h) * 2048.0f) : h;
    }
    *(f16x8*)(wpack + (size_t)linear * 8) = out;
}

// ---------------------------------------------------------------------------
// Kernel 1: embedding gather + x-half of z/r/h gate preactivations (+bias)
// ---------------------------------------------------------------------------
__global__ __launch_bounds__(128) void k_embed_xproj(
    const int* __restrict__ x, const float* __restrict__ emb,
    const float* __restrict__ Wz, const float* __restrict__ bz,
    const float* __restrict__ Wr, const float* __restrict__ br,
    const float* __restrict__ Wh, const float* __restrict__ bh,
    float* __restrict__ xproj) {
    int bt = blockIdx.x;
    int j = threadIdx.x;
    __shared__ float xe[ND];
    long tok = (long)x[bt];
    xe[j] = emb[tok * ND + j];
    __syncthreads();
    const float4* xe4 = (const float4*)xe;
    const float4* wz = (const float4*)(Wz + j * 2 * ND + ND);
    const float4* wr = (const float4*)(Wr + j * 2 * ND + ND);
    const float4* wh = (const float4*)(Wh + j * 2 * ND + ND);
    float az = bz[j], ar = br[j], ah = bh[j];
#pragma unroll 8
    for (int k = 0; k < ND / 4; ++k) {
        float4 xv = xe4[k];
        az += dot4(wz[k], xv);
        ar += dot4(wr[k], xv);
        ah += dot4(wh[k], xv);
    }
    float* o = xproj + (long)bt * 3 * ND;
    o[j] = az;
    o[ND + j] = ar;
    o[2 * ND + j] = ah;
}

// ---------------------------------------------------------------------------
// Kernel 2: the scan.  8 blocks (1 batch each) x 512 threads (8 waves,
// 2 waves/SIMD).  Exactly the R18 structure (best: 5.83 ms scan) with the
// single zero-register addition of folding 1/sqrt(32) into the q pack.
// R19's atv-in-regs + split MM lo-chains are REVERTED (they added ~8 live
// VGPRs and tipped remat/spill: WRITE_SIZE 416->480 KB, +0.22 ms).
// z,r,h,q HI-planes LDS-resident; lo-planes + k dual + vo/c1/c2 streamed.
// ---------------------------------------------------------------------------
__global__ __launch_bounds__(512, 2) void k_scan(
    const float* __restrict__ xproj, const float* __restrict__ init_states,
    const _Float16* __restrict__ wpack, const float* __restrict__ bvo,
    const float* __restrict__ bq, const float* __restrict__ bk,
    const float* __restrict__ bo, const float* __restrict__ bc,
    float* __restrict__ stout) {
    const int b = blockIdx.x, tid = threadIdx.x;
    const int lane = tid & 63, w = tid >> 6;
    const int lrow = lane & 15, lkb = lane >> 4;
    const int c = 16 * w + lrow;            // owned output column
    const bool vrow = (lkb < 2);            // C rows 4*lkb+i < 8 are real

    __shared__ float qf[NS][132], kf[NS][132];
    __shared__ float vofT[ND][8];           // transposed vo: [col][state-row]
    __shared__ float pf[8][NS][NS];
    // fp16 planes [8][128], XOR-swizzled.  0/1 st, 2/3 rs, 4/5 nw, 6/7 at.
    __shared__ _Float16 hp[8][8 * 128];
    // LDS-resident weight HI-planes, conflict-free [kt*512+t] (32 KB each)
    __shared__ f16x8 wzh[2048], wrh[2048], whh[2048], wqh[2048];

#define LOADW(BH, BL, m)                                                          \
    {                                                                             \
        const f16x8* base_ = (const f16x8*)wpack + ((m) << 12);                   \
        _Pragma("unroll") for (int kt_ = 0; kt_ < 4; ++kt_) {                     \
            BH[kt_] = base_[((kt_ * 2 + 0) << 9) + tid];                          \
            BL[kt_] = base_[((kt_ * 2 + 1) << 9) + tid];                          \
        }                                                                         \
    }

    // A-frag read: pad rows (lrow>=8) read row lrow&7 -> C pad rows duplicate
#define LDA(ph, pl_)                                                              \
    {                                                                             \
        _Pragma("unroll") for (int kt_ = 0; kt_ < 4; ++kt_) {                     \
            int off_ = ((lrow & 7) * 256 + kt_ * 64 + lkb * 16) ^ ((lrow & 7) << 4); \
            ah[kt_] = *(const f16x8*)((const char*)(ph) + off_);                  \
            al[kt_] = *(const f16x8*)((const char*)(pl_) + off_);                 \
        }                                                                         \
    }

    // B-frags fully from registers/L2 stream
#define MM(res, BH, BL, init0)                                                    \
    {                                                                             \
        f32x4 xh_ = {(init0), (init0), (init0), (init0)};                         \
        f32x4 xl_ = {0.f, 0.f, 0.f, 0.f};                                         \
        _Pragma("unroll") for (int kt_ = 0; kt_ < 4; ++kt_) {                     \
            xh_ = __builtin_amdgcn_mfma_f32_16x16x32_f16(ah[kt_], BH[kt_], xh_, 0, 0, 0); \
            xl_ = __builtin_amdgcn_mfma_f32_16x16x32_f16(al[kt_], BH[kt_], xl_, 0, 0, 0); \
            xl_ = __builtin_amdgcn_mfma_f32_16x16x32_f16(ah[kt_], BL[kt_], xl_, 0, 0, 0); \
        }                                                                         \
        _Pragma("unroll") for (int i_ = 0; i_ < 4; ++i_)                          \
            res[i_] = xh_[i_] + xl_[i_] * 4.8828125e-4f;                          \
    }

    // B hi from LDS plane, B lo streamed from L2 at the site
#define MM_HL(res, WH, m, init0)                                                  \
    {                                                                             \
        const f16x8* base_ = (const f16x8*)wpack + ((m) << 12);                   \
        f32x4 xh_ = {(init0), (init0), (init0), (init0)};                         \
        f32x4 xl_ = {0.f, 0.f, 0.f, 0.f};                                         \
        _Pragma("unroll") for (int kt_ = 0; kt_ < 4; ++kt_) {                     \
            f16x8 bh_ = WH[(kt_ << 9) + tid];                                     \
            f16x8 bl_ = base_[((kt_ * 2 + 1) << 9) + tid];                        \
            xh_ = __builtin_amdgcn_mfma_f32_16x16x32_f16(ah[kt_], bh_, xh_, 0, 0, 0); \
            xl_ = __builtin_amdgcn_mfma_f32_16x16x32_f16(al[kt_], bh_, xl_, 0, 0, 0); \
            xl_ = __builtin_amdgcn_mfma_f32_16x16x32_f16(ah[kt_], bl_, xl_, 0, 0, 0); \
        }                                                                         \
        _Pragma("unroll") for (int i_ = 0; i_ < 4; ++i_)                          \
            res[i_] = xh_[i_] + xl_[i_] * 4.8828125e-4f;                          \
    }

#define WRHL(pih, pil, row_, col_, val_)                                          \
    {                                                                             \
        float v_ = (val_);                                                        \
        _Float16 h_ = (_Float16)v_;                                               \
        _Float16 l_ = (_Float16)((v_ - (float)h_) * 2048.0f);                     \
        int off_ = ((row_)*256 + (col_)*2) ^ (((row_)&7) << 4);                   \
        *(_Float16*)((char*)hp[pih] + off_) = h_;                                 \
        *(_Float16*)((char*)hp[pil] + off_) = l_;                                 \
    }

    // ---- prologue: z,r,h,q HI planes into LDS ----
    {
        const f16x8* wp8 = (const f16x8*)wpack;
        for (int i = tid; i < 2048; i += 512) {
            int kt = i >> 9, tt = i & 511;
            wzh[i] = wp8[(0 << 12) + ((kt * 2 + 0) << 9) + tt];
            wrh[i] = wp8[(1 << 12) + ((kt * 2 + 0) << 9) + tt];
            whh[i] = wp8[(2 << 12) + ((kt * 2 + 0) << 9) + tt];
            wqh[i] = wp8[(3 << 12) + ((kt * 2 + 0) << 9) + tt];
        }
    }

    // ---- init: state fp32 into registers, hi/lo into st planes (rows 0-7) ----
    float stv[4];
#pragma unroll
    for (int i = 0; i < 4; ++i) {
        int r = 4 * lkb + i;
        float v = init_states[(r & 7) * ND + c];
        stv[i] = v;
        if (vrow) WRHL(0, 1, r, c, v);
    }

    // L2-streamed weights: k (resident if regalloc allows; remat accepted)
    f16x8 Bkh[4], Bkl[4];
    LOADW(Bkh, Bkl, 4);
    // rotating stream buffer: vo -> c1 -> c2 -> vo(t+1) ...
    f16x8 Sh[4], Sl[4];
    LOADW(Sh, Sl, 5);  // vo for t=0

    // bq pre-scaled to match the pre-scaled q weights (scale folded in pack)
    const float bqv = bq[c] * 0.17677669529663687f;
    const float bkv = bk[c], bvoc = bvo[c], bov = bo[c], bcv = bc[c];

    f16x8 ah[4], al[4];
    float zv[4], nwv[4];
    f32x4 ach, acl1, acl2;

    // xproj prefetch for t=0
    const float* xpb = xproj + ((size_t)b * NT) * 3 * ND;
    float xz = xpb[c], xr = xpb[ND + c], xh = xpb[2 * ND + c];

    BAR();

    for (int t = 0; t < NT; ++t) {
        // ---- A: z, r gates (hi-LDS / lo-L2), write r*state ----
        LDA(hp[0], hp[1]);
        float zp[4], rp[4];
        MM_HL(zp, wzh, 0, xz);
        MM_HL(rp, wrh, 1, xr);
#pragma unroll
        for (int i = 0; i < 4; ++i) zv[i] = rsigm(zp[i]);
        if (vrow) {
#pragma unroll
            for (int i = 0; i < 4; ++i) {
                float rs_ = rsigm(rp[i]) * stv[i];
                WRHL(2, 3, 4 * lkb + i, c, rs_);
            }
        }
        BAR();
        // ---- B: cand/new (hi-LDS / lo-L2) ----
        LDA(hp[2], hp[3]);
        float hpre[4];
        MM_HL(hpre, whh, 2, xh);
#pragma unroll
        for (int i = 0; i < 4; ++i) {
            float cand = ftanh(hpre[i]);
            float nv = (1.0f - zv[i]) * stv[i] + zv[i] * cand;
            nwv[i] = nv;
        }
        if (vrow) {
#pragma unroll
            for (int i = 0; i < 4; ++i) WRHL(4, 5, 4 * lkb + i, c, nwv[i]);
        }
        BAR();
        // ---- C: q (hi-LDS / lo-L2), k (L2), vo (stream) ----
        LDA(hp[4], hp[5]);  // nw fragments; stay live through D (c1)
        {
            float qp[4];
            MM_HL(qp, wqh, 3, bqv);
            if (vrow) {
#pragma unroll
                for (int i = 0; i < 4; ++i) qf[4 * lkb + i][c] = qp[i];
            }
            float kp[4];
            MM(kp, Bkh, Bkl, bkv);
            if (vrow) {
#pragma unroll
                for (int i = 0; i < 4; ++i) kf[4 * lkb + i][c] = kp[i];
            }
            float vp[4];
            MM(vp, Sh, Sl, bvoc);  // vo = nw@Wow^T + bvo
            LOADW(Sh, Sl, 6);      // stream c1
            if (vrow) {
                float4 vv;
                vv.x = vp[0]; vv.y = vp[1]; vv.z = vp[2]; vv.w = vp[3];
                *(float4*)&vofT[c][4 * lkb] = vv;  // one b128, transposed
            }
        }
        BAR();
        // ---- D: softmax (no-max, DPP-only reduce) + c1 + PV(-> at planes) ----
        {
            int hh = w >> 1;
            int sq = lane >> 3, skv = lane & 7;
            float s_ = 0.f;
#pragma unroll
            for (int j = 0; j < 8; ++j) {
                float4 qv = *(const float4*)&qf[sq][32 * hh + 4 * j];
                float4 kv4 = *(const float4*)&kf[skv][32 * hh + 4 * j];
                s_ += dot4(qv, kv4);
            }
            // scale folded into q pack; scores O(1..10): no-max is identical.
            float e_ = __expf(s_);
            float sm = e_;
            QPADD(sm, 0xB1);    // lane^1 (quad_perm)
            QPADD(sm, 0x4E);    // lane^2 (quad_perm)
            QPADD(sm, 0x141);   // other quad (ROW_HALF_MIRROR)
            pf[w][sq][skv] = e_ * __builtin_amdgcn_rcpf(sm);
        }
        // c1 accumulate (ah/al still = nw fragments); S = c1
        ach = (f32x4){bcv, bcv, bcv, bcv};
        acl1 = (f32x4){0.f, 0.f, 0.f, 0.f};
        acl2 = (f32x4){0.f, 0.f, 0.f, 0.f};
#pragma unroll
        for (int kt_ = 0; kt_ < 4; ++kt_) {
            ach = __builtin_amdgcn_mfma_f32_16x16x32_f16(ah[kt_], Sh[kt_], ach, 0, 0, 0);
            acl1 = __builtin_amdgcn_mfma_f32_16x16x32_f16(al[kt_], Sh[kt_], acl1, 0, 0, 0);
            acl2 = __builtin_amdgcn_mfma_f32_16x16x32_f16(ah[kt_], Sl[kt_], acl2, 0, 0, 0);
        }
        LOADW(Sh, Sl, 7);  // stream c2
        // PV: at = bo + P @ vo  (float4 reads of pf row & vofT col)
        if (vrow) {
            float4 voa = *(const float4*)&vofT[c][0];
            float4 vob = *(const float4*)&vofT[c][4];
#pragma unroll
            for (int i = 0; i < 4; ++i) {
                int r = 4 * lkb + i, pq = r & 7;
                float4 pa = *(const float4*)&pf[w][pq][0];
                float4 pb = *(const float4*)&pf[w][pq][4];
                float acc = bov + dot4(pa, voa) + dot4(pb, vob);
                WRHL(6, 7, r, c, acc);
            }
        }
        BAR();
        // ---- F: c2 + gate blend -> state regs + st planes ----
        LDA(hp[6], hp[7]);  // at fragments (A-operand of c2)
#pragma unroll
        for (int kt_ = 0; kt_ < 4; ++kt_) {
            ach = __builtin_amdgcn_mfma_f32_16x16x32_f16(ah[kt_], Sh[kt_], ach, 0, 0, 0);
            acl1 = __builtin_amdgcn_mfma_f32_16x16x32_f16(al[kt_], Sh[kt_], acl1, 0, 0, 0);
            acl2 = __builtin_amdgcn_mfma_f32_16x16x32_f16(ah[kt_], Sl[kt_], acl2, 0, 0, 0);
        }
        LOADW(Sh, Sl, 5);  // stream vo for t+1 (dead on last iter, harmless)
        if (vrow) {
#pragma unroll
            for (int i = 0; i < 4; ++i) {
                int r = 4 * lkb + i;
                int off_ = (r * 256 + c * 2) ^ ((r & 7) << 4);
                float hi = (float)*(_Float16*)((char*)hp[6] + off_);
                float lo = (float)*(_Float16*)((char*)hp[7] + off_);
                float atv = hi + lo * 4.8828125e-4f;
                float g = rsigm(ach[i] + (acl1[i] + acl2[i]) * 4.8828125e-4f);
                float sv = g * nwv[i] + (1.0f - g) * atv;
                stv[i] = sv;
                WRHL(0, 1, r, c, sv);
            }
        }
        // xproj prefetch for t+1
        {
            int tn = (t + 1 < NT) ? t + 1 : t;
            const float* xpn = xproj + ((size_t)(b * NT + tn)) * 3 * ND;
            xz = xpn[c];
            xr = xpn[ND + c];
            xh = xpn[2 * ND + c];
        }
        BAR();
    }
    if (vrow) {
#pragma unroll
        for (int i = 0; i < 4; ++i) {
            int r = 4 * lkb + i;
            stout[(size_t)b * NS * ND + r * ND + c] = stv[i];
        }
    }
#undef LOADW
#undef LDA
#undef MM
#undef MM_HL
#undef WRHL
}

// ---------------------------------------------------------------------------
// Kernel 3: out[b][o] = stflat[b] . Wout[o] + bout[o].  One wave per row.
// ---------------------------------------------------------------------------
__global__ __launch_bounds__(512) void k_out(
    const float* __restrict__ stflat, const float* __restrict__ Wout,
    const float* __restrict__ bout, float* __restrict__ out) {
    __shared__ float stl[NB][NS * ND];
    int tid = threadIdx.x;
    for (int idx = tid; idx < NB * NS * ND; idx += 512)
        stl[idx >> 10][idx & 1023] = stflat[idx];
    __syncthreads();
    int wave = tid >> 6, lane = tid & 63;
    int o = blockIdx.x * 8 + wave;
    float acc[NB];
#pragma unroll
    for (int b = 0; b < NB; ++b) acc[b] = 0.0f;
    const float4* wrow = (const float4*)(Wout + (size_t)o * (NS * ND));
#pragma unroll
    for (int i = 0; i < 4; ++i) {
        float4 wv = wrow[i * 64 + lane];
        int kb = (i * 64 + lane) * 4;
#pragma unroll
        for (int b = 0; b < NB; ++b) {
            float4 sv = *(const float4*)&stl[b][kb];
            acc[b] += dot4(wv, sv);
        }
    }
#pragma unroll
    for (int off = 32; off; off >>= 1) {
#pragma unroll
        for (int b = 0; b < NB; ++b) acc[b] += __shfl_down(acc[b], off);
    }
    if (lane == 0) {
        float bb = bout[o];
#pragma unroll
        for (int b = 0; b < NB; ++b) out[(size_t)b * NOUT + o] = acc[b] + bb;
    }
}

extern "C" void kernel_launch(void* const* d_in, const int* in_sizes, int n_in,
                              void* d_out, int out_size, void* d_ws, size_t ws_size,
                              hipStream_t stream) {
    const int* x = (const int*)d_in[0];
    const float* emb = (const float*)d_in[1];
    const float* init_states = (const float*)d_in[2];
    const float* Wz = (const float*)d_in[3];
    const float* bz = (const float*)d_in[4];
    const float* Wr = (const float*)d_in[5];
    const float* br = (const float*)d_in[6];
    const float* Wh = (const float*)d_in[7];
    const float* bh = (const float*)d_in[8];
    const float* Wq = (const float*)d_in[9];
    const float* bq = (const float*)d_in[10];
    const float* Wk = (const float*)d_in[11];
    const float* bk = (const float*)d_in[12];
    const float* Wv = (const float*)d_in[13];
    const float* bv = (const float*)d_in[14];
    const float* Wo = (const float*)d_in[15];
    const float* bo = (const float*)d_in[16];
    const float* Wc = (const float*)d_in[17];
    const float* bc = (const float*)d_in[18];
    const float* Wout = (const float*)d_in[19];
    const float* bout = (const float*)d_in[20];
    float* out = (float*)d_out;

    float* xproj = (float*)d_ws;                           // 12.58 MB
    float* stflat = xproj + (size_t)NB * NT * 3 * ND;      // 32 KB
    _Float16* wpack = (_Float16*)(stflat + NB * NS * ND);  // 8*4096*8 f16 = 512 KB
    float* Wow = (float*)(wpack + (size_t)8 * 4096 * 8);   // 64 KB
    float* bvo = Wow + ND * ND;                            // 512 B

    k_wow<<<ND, ND, 0, stream>>>(Wo, Wv, bv, Wow, bvo);
    k_pack<<<128, 256, 0, stream>>>(Wz, Wr, Wh, Wq, Wk, Wow, Wc, wpack);
    k_embed_xproj<<<NB * NT, 128, 0, stream>>>(x, emb, Wz, bz, Wr, br, Wh, bh, xproj);
    k_scan<<<NB, 512, 0, stream>>>(xproj, init_states, wpack, bvo, bq, bk, bo, bc, stflat);
    k_out<<<NOUT / 8, 512, 0, stream>>>(stflat, Wout, bout, out);
}